// Round 1
// baseline (416.987 us; speedup 1.0000x reference)
//
#include <hip/hip_runtime.h>
#include <hip/hip_bf16.h>

typedef __attribute__((ext_vector_type(8))) short short8;
typedef __attribute__((ext_vector_type(4))) float floatx4;

#define LDK 136   // padded LDS row length in bf16 elements

__device__ __forceinline__ unsigned short f2bf(float x) {
    unsigned u = __builtin_bit_cast(unsigned, x);
    return (unsigned short)((u + 0x7fffu + ((u >> 16) & 1u)) >> 16);
}

// One kernel for both passes.
// Pass1 (ACCUM=false): block=(b,r), s0=128*256, s1=256.
// Pass2 (ACCUM=true):  block=(b,c), s0=256, s1=128*256.
// Pipeline per block (3 barriers, V halves register-prefetched):
//   issue A loads -> issue V0 loads -> softmax(A)->P (wave-local rows)
//   -> bfrag (wave-local, NO barrier) -> cvt V0 -> V^T LDS (own rows, NO barrier)
//   -> issue V1 loads -> BARRIER -> MFMA0 -> BARRIER
//   -> cvt V1 -> V^T LDS + epilogue0 (overlapped) -> BARRIER -> MFMA1 -> epilogue1
template <bool ACCUM>
__global__ __launch_bounds__(512, 4) void gtrans(
    const float* __restrict__ atten, const float* __restrict__ value,
    float* __restrict__ out, const float* __restrict__ shiftp,
    const float* __restrict__ biasp, int s0, int s1)
{
    __shared__ short Buf[128 * LDK];   // 34816 B, reused: P rows -> V^T halves

    const int bi   = blockIdx.x;
    const int b    = bi >> 7;
    const int i    = bi & 127;
    const int tid  = threadIdx.x;
    const int lane = tid & 63;
    const int w    = tid >> 6;   // wave 0..7

    const float shift = shiftp[0];
    const float bias  = biasp[0];

    const float* abase = atten + (size_t)bi * (128 * 128);
    const float* vbase = value + (size_t)b * (128 * 128 * 256) + (size_t)i * s0;
    float*       obase = out   + (size_t)b * (128 * 128 * 256) + (size_t)i * s0;

    const int k0   = 2 * lane;        // staging: this lane's two k-columns
    const int dw   = 16 * w;          // wave's 16-row slice (P rows and V^T rows)
    const int rofs = lane >> 5;       // softmax: 2 rows per iteration
    const int acol = 4 * (lane & 31); // softmax: 4-element column base

    // ---- Issue A loads first (oldest in vmcnt queue: softmax waits leave V0 in flight)
    floatx4 aA[8];
#pragma unroll
    for (int j = 0; j < 8; ++j)
        aA[j] = *(const floatx4*)(abase + (dw + 2 * j + rofs) * 128 + acol);

    // ---- Issue V half-0 loads (latency hides under softmax)
    floatx4 aV[8];
    {
        const float* vp = vbase + (size_t)k0 * s1 + dw;
#pragma unroll
        for (int q = 0; q < 4; ++q) aV[q]     = *(const floatx4*)(vp + 4 * q);
#pragma unroll
        for (int q = 0; q < 4; ++q) aV[4 + q] = *(const floatx4*)(vp + s1 + 4 * q);
    }

    // ---- Softmax: rows dw..dw+15, 2 rows/iter, 32 lanes per row
#pragma unroll
    for (int j = 0; j < 8; ++j) {
        const int c = dw + 2 * j + rofs;
        const float cf = (float)c;
        float a[4];
#pragma unroll
        for (int e = 0; e < 4; ++e) {
            float d = (float)(acol + e) - cf;
            a[e] = aA[j][e] - (shift * d * d + bias);
        }
        float mx = fmaxf(fmaxf(a[0], a[1]), fmaxf(a[2], a[3]));
#pragma unroll
        for (int s = 1; s < 32; s <<= 1) mx = fmaxf(mx, __shfl_xor(mx, s, 32));
        float e0 = __expf(a[0] - mx), e1 = __expf(a[1] - mx);
        float e2 = __expf(a[2] - mx), e3 = __expf(a[3] - mx);
        float ssum = (e0 + e1) + (e2 + e3);
#pragma unroll
        for (int s = 1; s < 32; s <<= 1) ssum += __shfl_xor(ssum, s, 32);
        float r = 1.0f / ssum;
        unsigned long long p =
              (unsigned long long)f2bf(e0 * r)
            | ((unsigned long long)f2bf(e1 * r) << 16)
            | ((unsigned long long)f2bf(e2 * r) << 32)
            | ((unsigned long long)f2bf(e3 * r) << 48);
        *(unsigned long long*)(&Buf[c * LDK + acol]) = p;
    }

    // ---- B fragments: wave-local rows -> NO barrier needed
    short8 bfrag[4];
    const int am = lane & 15;
    const int kq = (lane >> 4) * 8;
    {
        const int n = dw + am;
#pragma unroll
        for (int ks = 0; ks < 4; ++ks)
            bfrag[ks] = *(const short8*)(&Buf[n * LDK + ks * 32 + kq]);
    }

    // ---- Stage V^T half-0: overwrites this wave's OWN P rows -> NO barrier needed.
    // Packed u32 writes, contiguous across lanes -> bank-conflict-free.
#pragma unroll
    for (int j = 0; j < 16; ++j) {
        unsigned lo = f2bf(aV[j >> 2][j & 3]);
        unsigned hi = f2bf(aV[4 + (j >> 2)][j & 3]);
        *(unsigned*)(&Buf[(dw + j) * LDK + k0]) = lo | (hi << 16);
    }

    // ---- Issue V half-1 loads (register loads survive s_barrier: in flight across MFMA0)
    {
        const float* vp = vbase + (size_t)k0 * s1 + 128 + dw;
#pragma unroll
        for (int q = 0; q < 4; ++q) aV[q]     = *(const floatx4*)(vp + 4 * q);
#pragma unroll
        for (int q = 0; q < 4; ++q) aV[4 + q] = *(const floatx4*)(vp + s1 + 4 * q);
    }

    __syncthreads();   // V^T half-0 complete across waves

    floatx4 acc[8];
#pragma unroll
    for (int t = 0; t < 8; ++t) acc[t] = (floatx4)0.0f;
#pragma unroll
    for (int ks = 0; ks < 4; ++ks)
#pragma unroll
        for (int t = 0; t < 8; ++t) {
            short8 af = *(const short8*)(&Buf[(t * 16 + am) * LDK + ks * 32 + kq]);
            acc[t] = __builtin_amdgcn_mfma_f32_16x16x32_bf16(af, bfrag[ks], acc[t], 0, 0, 0);
        }

    __syncthreads();   // all waves done reading half-0

    // ---- Stage V^T half-1 and epilogue half-0, overlapped between barriers
#pragma unroll
    for (int j = 0; j < 16; ++j) {
        unsigned lo = f2bf(aV[j >> 2][j & 3]);
        unsigned hi = f2bf(aV[4 + (j >> 2)][j & 3]);
        *(unsigned*)(&Buf[(dw + j) * LDK + k0]) = lo | (hi << 16);
    }
    {
        float* orow = obase + (size_t)(dw + am) * s1 + (lane >> 4) * 4;
#pragma unroll
        for (int t = 0; t < 8; ++t) {
            float* p = orow + t * 16;
            floatx4 res = acc[t];
            if (ACCUM) res = res + *(const floatx4*)p;
            *(floatx4*)p = res;
        }
    }

    __syncthreads();   // V^T half-1 complete

#pragma unroll
    for (int t = 0; t < 8; ++t) acc[t] = (floatx4)0.0f;
#pragma unroll
    for (int ks = 0; ks < 4; ++ks)
#pragma unroll
        for (int t = 0; t < 8; ++t) {
            short8 af = *(const short8*)(&Buf[(t * 16 + am) * LDK + ks * 32 + kq]);
            acc[t] = __builtin_amdgcn_mfma_f32_16x16x32_bf16(af, bfrag[ks], acc[t], 0, 0, 0);
        }
    {
        float* orow = obase + (size_t)(dw + am) * s1 + 128 + (lane >> 4) * 4;
#pragma unroll
        for (int t = 0; t < 8; ++t) {
            float* p = orow + t * 16;
            floatx4 res = acc[t];
            if (ACCUM) res = res + *(const floatx4*)p;
            *(floatx4*)p = res;
        }
    }
}

extern "C" void kernel_launch(void* const* d_in, const int* in_sizes, int n_in,
                              void* d_out, int out_size, void* d_ws, size_t ws_size,
                              hipStream_t stream) {
    const float* atten_x = (const float*)d_in[1];
    const float* atten_y = (const float*)d_in[2];
    const float* value   = (const float*)d_in[3];
    const float* shiftp  = (const float*)d_in[4];
    const float* biasp   = (const float*)d_in[5];
    float* out = (float*)d_out;

    dim3 grid(1024), block(512);
    // Pass 1: out = einsum('brck,brkd->brcd', softmax(Ax+gx), value)
    gtrans<false><<<grid, block, 0, stream>>>(atten_x, value, out, shiftp, biasp,
                                              128 * 256, 256);
    // Pass 2: out += einsum('bcrk,bkcd->brcd', softmax(Ay+gy), value)
    gtrans<true><<<grid, block, 0, stream>>>(atten_y, value, out, shiftp, biasp,
                                             256, 128 * 256);
}

// Round 2
// 409.388 us; speedup vs baseline: 1.0186x; 1.0186x over previous
//
#include <hip/hip_runtime.h>

typedef __attribute__((ext_vector_type(8))) short short8;
typedef __attribute__((ext_vector_type(4))) float floatx4;

#define LDK 136                    // padded LDS row (bf16 units): 272 B, 16B-aligned
#define LDS_BYTES (256 * LDK * 2)  // 69632 B: full V^T (256 d-rows x 128 k)

__device__ __forceinline__ unsigned f2bf1(float x) {
    unsigned u = __builtin_bit_cast(unsigned, x);
    return (u + 0x7fffu + ((u >> 16) & 1u)) >> 16;
}
__device__ __forceinline__ unsigned packbf(float lo, float hi) {
    return f2bf1(lo) | (f2bf1(hi) << 16);
}

// Pass1 (ACCUM=false): block=(b,r), s0=128*256, s1=256.
// Pass2 (ACCUM=true):  block=(b,c), s0=256, s1=128*256.
// Schedule: issue A(8 dwordx4) + ALL V(16 dwordx4) -> softmax (A drains, V flies)
//   -> bfrag in-register (row-per-lane layout, no LDS) -> stage full V^T
//   -> (pass2: prefetch out g0) -> lgkmcnt-only raw barrier (ONE barrier/block)
//   -> 4 groups x {prefetch out g+1, 16 MFMA, epilogue}.
template <bool ACCUM>
__global__ __launch_bounds__(512, 4) void gtrans(
    const float* __restrict__ atten, const float* __restrict__ value,
    float* __restrict__ out, const float* __restrict__ shiftp,
    const float* __restrict__ biasp, int s0, int s1)
{
    extern __shared__ short Buf[];
    unsigned* Buf32 = (unsigned*)Buf;

    const int bi   = blockIdx.x;
    const int b    = bi >> 7;
    const int i    = bi & 127;
    const int tid  = threadIdx.x;
    const int lane = tid & 63;
    const int w    = tid >> 6;

    const float shift = shiftp[0];
    const float bias  = biasp[0];

    const float* abase = atten + (size_t)bi * (128 * 128);
    const float* vbase = value + (size_t)b * (128 * 128 * 256) + (size_t)i * s0;
    float*       obase = out   + (size_t)b * (128 * 128 * 256) + (size_t)i * s0;

    const int rrow = 16 * w + (lane & 15);   // this lane's c-row (softmax + output)
    const int kq8  = (lane >> 4) * 8;        // k-subchunk base (MFMA fragment layout)
    const int k0   = 16 * w + 2 * (lane >> 3); // V staging: even k-row
    const int d0   = 4 * (lane & 7);           // V staging: d-quad base

    // ---- Issue A loads first (oldest in queue: softmax waits leave V in flight)
    floatx4 aA[8];
#pragma unroll
    for (int ks = 0; ks < 4; ++ks) {
        const float* ap = abase + rrow * 128 + ks * 32 + kq8;
        aA[2 * ks]     = *(const floatx4*)(ap);
        aA[2 * ks + 1] = *(const floatx4*)(ap + 4);
    }
    // ---- Issue ALL V loads (16 dwordx4/thread; 8 even+odd k-row pairs, d quads)
    floatx4 va[8], vb[8];
    {
        const float* vp0 = vbase + (size_t)k0 * s1 + d0;
        const float* vp1 = vp0 + s1;
#pragma unroll
        for (int q = 0; q < 8; ++q) va[q] = *(const floatx4*)(vp0 + 32 * q);
#pragma unroll
        for (int q = 0; q < 8; ++q) vb[q] = *(const floatx4*)(vp1 + 32 * q);
    }
    __builtin_amdgcn_sched_barrier(0);   // pin: keep all loads issued up front

    // ---- Softmax, row-per-lane: lane holds 32 k-values of row rrow.
    // 4 lanes (l, l^16, l^32, l^48) share a row -> 2-shuffle reduction.
    floatx4 e8[8];
    {
        float mx = -1e30f;
#pragma unroll
        for (int j = 0; j < 8; ++j) {
            const int kb = (j >> 1) * 32 + kq8 + (j & 1) * 4;
            floatx4 v = aA[j];
            floatx4 t;
#pragma unroll
            for (int e = 0; e < 4; ++e) {
                float d = (float)(kb + e - rrow);
                t[e] = v[e] - (shift * d * d + bias);
            }
            e8[j] = t;
            mx = fmaxf(mx, fmaxf(fmaxf(t[0], t[1]), fmaxf(t[2], t[3])));
        }
        mx = fmaxf(mx, __shfl_xor(mx, 16, 64));
        mx = fmaxf(mx, __shfl_xor(mx, 32, 64));
        float ssum = 0.0f;
#pragma unroll
        for (int j = 0; j < 8; ++j) {
            floatx4 t = e8[j];
#pragma unroll
            for (int e = 0; e < 4; ++e) t[e] = __expf(t[e] - mx);
            e8[j] = t;
            ssum += (t[0] + t[1]) + (t[2] + t[3]);
        }
        ssum += __shfl_xor(ssum, 16, 64);
        ssum += __shfl_xor(ssum, 32, 64);
        float r = 1.0f / ssum;
#pragma unroll
        for (int j = 0; j < 8; ++j) {
#pragma unroll
            for (int e = 0; e < 4; ++e) e8[j][e] *= r;
        }
    }

    // ---- B fragments directly in registers (zero LDS, zero extra shuffles)
    short8 bfrag[4];
#pragma unroll
    for (int ks = 0; ks < 4; ++ks) {
        union { short8 s; unsigned u[4]; } uu;
        floatx4 lo = e8[2 * ks], hi = e8[2 * ks + 1];
        uu.u[0] = packbf(lo[0], lo[1]);
        uu.u[1] = packbf(lo[2], lo[3]);
        uu.u[2] = packbf(hi[0], hi[1]);
        uu.u[3] = packbf(hi[2], hi[3]);
        bfrag[ks] = uu.s;
    }

    // ---- Stage full V^T: packed u32 (k-pair) writes, rows = d 0..255
#pragma unroll
    for (int q = 0; q < 8; ++q)
#pragma unroll
        for (int e = 0; e < 4; ++e)
            Buf32[(d0 + 32 * q + e) * (LDK / 2) + (k0 >> 1)] = packbf(va[q][e], vb[q][e]);

    // ---- Pass2: prefetch out group 0 (stays in flight across the raw barrier)
    const int dq = 4 * (lane >> 4);
    float* orow = obase + (size_t)rrow * s1 + dq;
    floatx4 aO[4];
    if (ACCUM) {
#pragma unroll
        for (int t = 0; t < 4; ++t) aO[t] = *(const floatx4*)(orow + t * 16);
    }

    // ---- ONE barrier: drain LDS writes only; global loads stay outstanding
    __builtin_amdgcn_sched_barrier(0);
    asm volatile("s_waitcnt lgkmcnt(0)" ::: "memory");
    __builtin_amdgcn_s_barrier();

    // ---- 4 groups of 4 d-tiles: prefetch next out, 16 MFMA, epilogue
#pragma unroll
    for (int g = 0; g < 4; ++g) {
        floatx4 aN[4];
        if (ACCUM && g < 3) {
#pragma unroll
            for (int t = 0; t < 4; ++t)
                aN[t] = *(const floatx4*)(orow + (g + 1) * 64 + t * 16);
        }
        floatx4 acc[4];
#pragma unroll
        for (int t = 0; t < 4; ++t) acc[t] = (floatx4)0.0f;
#pragma unroll
        for (int tt = 0; tt < 4; ++tt) {
            const short* base = &Buf[((g * 4 + tt) * 16 + (lane & 15)) * LDK + kq8];
#pragma unroll
            for (int ks = 0; ks < 4; ++ks) {
                short8 af = *(const short8*)(base + ks * 32);
                acc[tt] = __builtin_amdgcn_mfma_f32_16x16x32_bf16(af, bfrag[ks], acc[tt], 0, 0, 0);
            }
        }
#pragma unroll
        for (int t = 0; t < 4; ++t) {
            floatx4 res = acc[t];
            if (ACCUM) res = res + aO[t];
            *(floatx4*)(orow + g * 64 + t * 16) = res;
        }
        if (ACCUM && g < 3) {
#pragma unroll
            for (int t = 0; t < 4; ++t) aO[t] = aN[t];
        }
    }
}

extern "C" void kernel_launch(void* const* d_in, const int* in_sizes, int n_in,
                              void* d_out, int out_size, void* d_ws, size_t ws_size,
                              hipStream_t stream) {
    const float* atten_x = (const float*)d_in[1];
    const float* atten_y = (const float*)d_in[2];
    const float* value   = (const float*)d_in[3];
    const float* shiftp  = (const float*)d_in[4];
    const float* biasp   = (const float*)d_in[5];
    float* out = (float*)d_out;

    static bool inited = false;
    if (!inited) {
        hipFuncSetAttribute((const void*)&gtrans<false>,
                            hipFuncAttributeMaxDynamicSharedMemorySize, LDS_BYTES);
        hipFuncSetAttribute((const void*)&gtrans<true>,
                            hipFuncAttributeMaxDynamicSharedMemorySize, LDS_BYTES);
        inited = true;
    }

    dim3 grid(1024), block(512);
    // Pass 1: out = einsum('brck,brkd->brcd', softmax(Ax+gx), value)
    gtrans<false><<<grid, block, LDS_BYTES, stream>>>(atten_x, value, out, shiftp, biasp,
                                                      128 * 256, 256);
    // Pass 2: out += einsum('bcrk,bkcd->brcd', softmax(Ay+gy), value)
    gtrans<true><<<grid, block, LDS_BYTES, stream>>>(atten_y, value, out, shiftp, biasp,
                                                     256, 128 * 256);
}